// Round 12
// baseline (1330.670 us; speedup 1.0000x reference)
//
#include <hip/hip_runtime.h>
#include <stdint.h>

#define NN 100000
#define NNP 100096          // NN padded to multiple of 128
#define NE 200000
#define NEP 200064          // NE padded to multiple of 128
#define NT 600000
#define HID 256

typedef __attribute__((ext_vector_type(8))) short bf16x8;
typedef __attribute__((ext_vector_type(4))) float f32x4;

__device__ __forceinline__ float bf2f(unsigned short u) {
    union { unsigned int i; float f; } x; x.i = ((unsigned int)u) << 16; return x.f;
}
__device__ __forceinline__ unsigned short f2bf(float f) {
    union { float f; unsigned int i; } x; x.f = f;
    unsigned int r = (x.i + 0x7FFFu + ((x.i >> 16) & 1u)) >> 16;
    return (unsigned short)r;
}

// async global->LDS, 16B per lane; LDS dest = wave-uniform base + lane*16
__device__ __forceinline__ void gload16(const void* g, void* l) {
    __builtin_amdgcn_global_load_lds(
        (const __attribute__((address_space(1))) void*)g,
        (__attribute__((address_space(3))) void*)l, 16, 0, 0);
}

// ---------------------------------------------------------------------------
// m97-style GEMM core, OPERAND-SWAPPED: acc = mfma(B_frag, A_frag) yields C^T
// fragments, so each lane's 4 acc f32 = 4 CONSECUTIVE COLUMNS of one row:
//   row = row0 + wr*64 + mi*16 + (lane&15)       [per-lane]
//   col = col0 + wc*64 + ni*16 + (lane>>4)*4 + reg
// -> C-write is 16 x 8B ushort4 (or 16B float4) stores instead of 64 x 2B.
// 4 waves (2x2), wave tile 64x64, BK=64, 32 KB LDS, 2-barrier loop.
// REGISTER BUDGET [round-8/10 lesson]: pool = 512 wave-regs/SIMD (unified
// VGPR+AGPR). Needs 64 acc + ~60 VGPR = 124; bounds(256,4) caps 128: OK.
// (256,5) cap=102 and (512,6) cap=85 both spilled acc to scratch.
// ---------------------------------------------------------------------------
template<int FLAGS, bool CBF>
__device__ __forceinline__
void gemm128_core(const unsigned short* __restrict__ A,
                  const unsigned short* __restrict__ BT,
                  const float* __restrict__ bias,
                  const unsigned short* __restrict__ res,
                  void* __restrict__ Cv, int row0, int col0,
                  int Mreal, int Kpad,
                  unsigned short* Asb, unsigned short* Bsb)
{
    const int t    = threadIdx.x;
    const int lane = t & 63;
    const int wv   = t >> 6;          // 0..3
    const int wr   = wv >> 1;         // wave row half
    const int wc   = wv & 1;          // wave col half
    const int l15  = lane & 15;
    const int lk   = lane >> 4;
    const int sub  = lane >> 3;       // staging sub-row 0..7
    const int schk = lane & 7;        // staging 16B chunk 0..7

    f32x4 acc[4][4];
#pragma unroll
    for (int i = 0; i < 4; ++i)
#pragma unroll
        for (int j = 0; j < 4; ++j) acc[i][j] = (f32x4){0.f, 0.f, 0.f, 0.f};

    const int nt = Kpad >> 6;
    for (int kt = 0; kt < nt; ++kt) {
        const int k0 = kt << 6;
        // stage A tile 128x64 (16 segs of 8 rows; wave wv does segs wv*4+j)
#pragma unroll
        for (int j = 0; j < 4; ++j) {
            const int ii = wv * 4 + j;
            const int r  = ii * 8 + sub;
            const int cg = schk ^ (r & 7);
            gload16(A + (size_t)(row0 + r) * Kpad + k0 + cg * 8, Asb + ii * 512);
        }
        // stage B tile 128x64 (B rows = output cols col0..col0+127)
#pragma unroll
        for (int j = 0; j < 4; ++j) {
            const int ii = wv * 4 + j;
            const int r  = ii * 8 + sub;
            const int cg = schk ^ (r & 7);
            gload16(BT + (size_t)(col0 + r) * Kpad + k0 + cg * 8, Bsb + ii * 512);
        }
        __syncthreads();     // compiler drains vmcnt before s_barrier
#pragma unroll
        for (int ks = 0; ks < 2; ++ks) {
            bf16x8 af[4], bfg[4];
#pragma unroll
            for (int mi = 0; mi < 4; ++mi) {
                const int r = wr * 64 + mi * 16 + l15;
                const int c = ks * 4 + lk;
                af[mi] = *(const bf16x8*)((const char*)Asb
                          + r * 128 + ((c ^ (r & 7)) << 4));
            }
#pragma unroll
            for (int ni = 0; ni < 4; ++ni) {
                const int r = wc * 64 + ni * 16 + l15;
                const int c = ks * 4 + lk;
                bfg[ni] = *(const bf16x8*)((const char*)Bsb
                           + r * 128 + ((c ^ (r & 7)) << 4));
            }
            // swapped operands: D = B^T * A^T = C^T fragments
#pragma unroll
            for (int mi = 0; mi < 4; ++mi)
#pragma unroll
                for (int ni = 0; ni < 4; ++ni)
                    acc[mi][ni] = __builtin_amdgcn_mfma_f32_16x16x32_bf16(
                        bfg[ni], af[mi], acc[mi][ni], 0, 0, 0);
        }
        __syncthreads();     // reads done before next stage overwrites
    }

    // epilogue (C^T layout): row per-lane, 4 consecutive cols per acc
#pragma unroll
    for (int mi = 0; mi < 4; ++mi) {
        const int row = row0 + wr * 64 + mi * 16 + l15;
        if (row >= Mreal) continue;
#pragma unroll
        for (int ni = 0; ni < 4; ++ni) {
            const int colb = col0 + wc * 64 + ni * 16 + lk * 4;
            float4 o = make_float4(acc[mi][ni][0], acc[mi][ni][1],
                                   acc[mi][ni][2], acc[mi][ni][3]);
            if (FLAGS & 2) {
                const float4 bi = *reinterpret_cast<const float4*>(bias + colb);
                o.x += bi.x; o.y += bi.y; o.z += bi.z; o.w += bi.w;
            }
            if (FLAGS & 1) {
                o.x = fmaxf(o.x, 0.f); o.y = fmaxf(o.y, 0.f);
                o.z = fmaxf(o.z, 0.f); o.w = fmaxf(o.w, 0.f);
            }
            if (FLAGS & 4) {
                const ushort4 rv = *reinterpret_cast<const ushort4*>(
                    res + (size_t)row * HID + colb);
                o.x += bf2f(rv.x); o.y += bf2f(rv.y);
                o.z += bf2f(rv.z); o.w += bf2f(rv.w);
            }
            if (CBF) {
                ushort4 ov;
                ov.x = f2bf(o.x); ov.y = f2bf(o.y);
                ov.z = f2bf(o.z); ov.w = f2bf(o.w);
                *reinterpret_cast<ushort4*>(
                    (unsigned short*)Cv + (size_t)row * HID + colb) = ov;
            } else {
                *reinterpret_cast<float4*>(
                    (float*)Cv + (size_t)row * HID + colb) = o;
            }
        }
    }
}

// XCD-aware swizzle [T1]: x = xcd + 8*(member + MEMBERS*local_group).
template<int FLAGS, bool CBF>
__global__ __launch_bounds__(256, 4)
void gemm128(const unsigned short* __restrict__ A,
             const unsigned short* __restrict__ BT,
             const float* __restrict__ bias,
             const unsigned short* __restrict__ res,
             void* __restrict__ Cv, int Mtiles, int Mreal, int Kpad)
{
    __shared__ alignas(16) unsigned short Asb[128 * 64];
    __shared__ alignas(16) unsigned short Bsb[128 * 64];
    const int x   = blockIdx.x;
    const int xcd = x & 7;
    const int ii  = x >> 3;
    const int g   = (ii >> 1) * 8 + xcd;     // tile-group = M tile
    const int ch  = ii & 1;
    if (g >= Mtiles) return;
    gemm128_core<FLAGS, CBF>(A, BT, bias, res, Cv, g * 128, ch * 128,
                             Mreal, Kpad, Asb, Bsb);
}

// qkv: grid.x = Mtiles8 * 6; 6 members (3 proj x 2 halves) share one A tile
__global__ __launch_bounds__(256, 4)
void gemm128_qkv(const unsigned short* __restrict__ A,
                 const unsigned short* __restrict__ BTq,
                 const unsigned short* __restrict__ BTk,
                 const unsigned short* __restrict__ BTv,
                 unsigned short* __restrict__ Cq,
                 unsigned short* __restrict__ Ck,
                 unsigned short* __restrict__ Cvp, int Mtiles)
{
    __shared__ alignas(16) unsigned short Asb[128 * 64];
    __shared__ alignas(16) unsigned short Bsb[128 * 64];
    const int x   = blockIdx.x;
    const int xcd = x & 7;
    const int ii  = x >> 3;
    const int g   = (ii / 6) * 8 + xcd;
    const int j   = ii % 6;
    if (g >= Mtiles) return;
    const int proj = j >> 1;
    const int ch   = j & 1;
    const unsigned short* BT = (proj == 0) ? BTq : (proj == 1) ? BTk : BTv;
    unsigned short*       C  = (proj == 0) ? Cq  : (proj == 1) ? Ck  : Cvp;
    gemm128_core<0, true>(A, BT, nullptr, nullptr, C, g * 128, ch * 128,
                          NE, 256, Asb, Bsb);
}

// ---------------------------------------------------------------------------
__global__ __launch_bounds__(256)
void wconv(const float* __restrict__ W, unsigned short* __restrict__ BT,
           int Kreal, int Kpad)
{
    const int idx = blockIdx.x * 256 + threadIdx.x;
    const int n = idx / Kpad, kp = idx - n * Kpad;
    float v = (kp < Kreal) ? W[(size_t)kp * HID + n] : 0.f;
    BT[idx] = f2bf(v);
}

__global__ __launch_bounds__(256)
void wconv10(const float* __restrict__ Wq, const float* __restrict__ Wk,
             const float* __restrict__ Wv, const float* __restrict__ L1w,
             const float* __restrict__ L2w, unsigned short* __restrict__ outbase)
{
    const int y = blockIdx.y;
    const int l = y / 5, which = y - l * 5;
    const float* src;
    switch (which) {
        case 0: src = Wq;  break;
        case 1: src = Wk;  break;
        case 2: src = Wv;  break;
        case 3: src = L1w; break;
        default: src = L2w; break;
    }
    src += (size_t)l * 65536;
    const int idx = blockIdx.x * 256 + threadIdx.x;
    const int n = idx >> 8, kp = idx & 255;
    outbase[(size_t)y * 65536 + idx] = f2bf(src[(size_t)kp * HID + n]);
}

// ---------------------------------------------------------------------------
__global__ __launch_bounds__(256)
void build_initA(const float* __restrict__ atom, const float* __restrict__ edge,
                 const int* __restrict__ src, unsigned short* __restrict__ out)
{
    const long total = (long)NE * 192;
    long idx = (long)blockIdx.x * blockDim.x + threadIdx.x;
    if (idx >= total) return;
    const int e = (int)(idx / 192);
    const int c = (int)(idx - (long)e * 192);
    float v = 0.f;
    if (c < 133)      v = atom[(size_t)src[e] * 133 + c];
    else if (c < 147) v = edge[(size_t)e * 14 + (c - 133)];
    out[idx] = f2bf(v);
}

__global__ __launch_bounds__(256)
void build_finalA(const float* __restrict__ atom, const float* __restrict__ fsum,
                  unsigned short* __restrict__ out)
{
    const long total = (long)NNP * 448;
    long idx = (long)blockIdx.x * blockDim.x + threadIdx.x;
    if (idx >= total) return;
    const int n = (int)(idx / 448);
    const int c = (int)(idx - (long)n * 448);
    float v = 0.f;
    if (n < NN) {
        if (c < 133)      v = atom[(size_t)n * 133 + c];
        else if (c < 389) v = fsum[(size_t)n * 256 + (c - 133)];
    }
    out[idx] = f2bf(v);
}

// ---------------------------------------------------------------------------
// CSR build
// ---------------------------------------------------------------------------
__global__ __launch_bounds__(256)
void count_keys(const int* __restrict__ key, int n, int nkeys, int* __restrict__ cnt)
{
    const int i = blockIdx.x * 256 + threadIdx.x;
    if (i < n) {
        const int kk = key[i];
        if ((unsigned)kk < (unsigned)nkeys) atomicAdd(&cnt[kk], 1);
    }
}

__global__ __launch_bounds__(256)
void fill_lists(const int* __restrict__ key, int n, int nkeys, int cap,
                int* __restrict__ cur, int* __restrict__ list)
{
    const int i = blockIdx.x * 256 + threadIdx.x;
    if (i < n) {
        const int kk = key[i];
        if ((unsigned)kk >= (unsigned)nkeys) return;
        const int pos = atomicAdd(&cur[kk], 1);
        if ((unsigned)pos < (unsigned)cap) list[pos] = i;
    }
}

// tkj[p] = idx_kj[tlist[p]]  (collapses the 2-level dependent gather chain)
__global__ __launch_bounds__(256)
void build_tripkj(const int* __restrict__ tlist, const int* __restrict__ idx_kj,
                  int* __restrict__ tkj)
{
    const int p = blockIdx.x * 256 + threadIdx.x;
    if (p >= NT) return;
    const int tt = tlist[p];
    int kj = -1;
    if ((unsigned)tt < (unsigned)NT) kj = idx_kj[tt];
    tkj[p] = kj;
}

__global__ __launch_bounds__(256)
void scan1(const int* __restrict__ in, int n, int* __restrict__ excl,
           int* __restrict__ part)
{
    __shared__ int sh[256];
    const int t = threadIdx.x;
    const int base = blockIdx.x * 1024 + t * 4;
    int v[4]; int s = 0;
#pragma unroll
    for (int j = 0; j < 4; ++j) { v[j] = (base + j < n) ? in[base + j] : 0; s += v[j]; }
    sh[t] = s; __syncthreads();
    for (int off = 1; off < 256; off <<= 1) {
        int x = (t >= off) ? sh[t - off] : 0;
        __syncthreads();
        sh[t] += x;
        __syncthreads();
    }
    int ex = sh[t] - s;
#pragma unroll
    for (int j = 0; j < 4; ++j) { if (base + j < n) excl[base + j] = ex; ex += v[j]; }
    if (t == 255) part[blockIdx.x] = sh[255];
}

__global__ __launch_bounds__(256)
void scan2(int* __restrict__ part, int nparts)
{
    __shared__ int sh[256];
    const int t = threadIdx.x;
    const int v = (t < nparts) ? part[t] : 0;
    sh[t] = v; __syncthreads();
    for (int off = 1; off < 256; off <<= 1) {
        int x = (t >= off) ? sh[t - off] : 0;
        __syncthreads();
        sh[t] += x;
        __syncthreads();
    }
    if (t < nparts) part[t] = sh[t] - v;
}

// offs[i] = cur[i] = excl[i] + part[i/1024]; offs[n] = total.
// counts/cur intentionally NOT restrict (they alias); read c before write.
__global__ __launch_bounds__(256)
void scan3(const int* __restrict__ excl, const int* __restrict__ part,
           const int* counts, int n, int* __restrict__ offs, int* cur)
{
    const int i = blockIdx.x * 256 + threadIdx.x;
    if (i >= n) return;
    const int v = excl[i] + part[i >> 10];
    const int c = counts[i];
    offs[i] = v;
    cur[i] = v;
    if (i == n - 1) offs[n] = v + c;
}

// ---------------------------------------------------------------------------
// Fused attention gather: 32 lanes per edge (2 edges/wave), bf16x8 loads,
// flattened kj list (tkj) with one-deep prefetch.
// ---------------------------------------------------------------------------
__global__ __launch_bounds__(256)
void gather_v(const unsigned short* __restrict__ q, const unsigned short* __restrict__ k,
              const unsigned short* __restrict__ v,
              const int* __restrict__ toff, const int* __restrict__ tkj,
              unsigned short* __restrict__ vc)
{
    const long gtid = (long)blockIdx.x * blockDim.x + threadIdx.x;
    const int w    = (int)(gtid >> 5);
    const int lane = threadIdx.x & 31;
    if (w >= NE) return;
    int beg = toff[w], end = toff[w + 1];
    if (beg < 0) beg = 0;
    if (end > NT) end = NT;

    const bf16x8 kv = *(const bf16x8*)(k + (size_t)w * HID + lane * 8);
    float kf[8];
#pragma unroll
    for (int j = 0; j < 8; ++j) kf[j] = bf2f((unsigned short)kv[j]);

    float av[8];
#pragma unroll
    for (int j = 0; j < 8; ++j) av[j] = 0.f;
    float den = 0.f;

    int kj_next = (beg < end) ? tkj[beg] : -1;
    for (int p = beg; p < end; ++p) {
        const int kj = kj_next;
        if (p + 1 < end) kj_next = tkj[p + 1];
        if ((unsigned)kj >= (unsigned)NE) continue;
        const bf16x8 qv = *(const bf16x8*)(q + (size_t)kj * HID + lane * 8);
        float s = 0.f;
#pragma unroll
        for (int j = 0; j < 8; ++j) s += bf2f((unsigned short)qv[j]) * kf[j];
        s += __shfl_xor(s, 1);
        s += __shfl_xor(s, 2);
        const float lr = (s > 0.f) ? s : 0.2f * s;
        const float a  = __expf(lr);
        den += a;
        const bf16x8 vv = *(const bf16x8*)(v + (size_t)kj * HID + lane * 8);
#pragma unroll
        for (int j = 0; j < 8; ++j) av[j] += a * bf2f((unsigned short)vv[j]);
    }
    const float inv = (den != 0.f) ? 1.f / den : 0.f;
    bf16x8 o;
#pragma unroll
    for (int j = 0; j < 8; ++j) o[j] = (short)f2bf(av[j] * inv);
    *(bf16x8*)(vc + (size_t)w * HID + lane * 8) = o;
}

// ---------------------------------------------------------------------------
// edge->node gather: 32 lanes per node, bf16x8 loads, f32 out
// ---------------------------------------------------------------------------
__global__ __launch_bounds__(256)
void gather_node(const unsigned short* __restrict__ feats,
                 const int* __restrict__ noff, const int* __restrict__ nlist,
                 float* __restrict__ fsum)
{
    const long gtid = (long)blockIdx.x * blockDim.x + threadIdx.x;
    const int w    = (int)(gtid >> 5);
    const int lane = threadIdx.x & 31;
    if (w >= NN) return;
    int beg = noff[w], end = noff[w + 1];
    if (beg < 0) beg = 0;
    if (end > NE) end = NE;
    float av[8];
#pragma unroll
    for (int j = 0; j < 8; ++j) av[j] = 0.f;
    int e_next = (beg < end) ? nlist[beg] : -1;
    for (int p = beg; p < end; ++p) {
        const int e = e_next;
        if (p + 1 < end) e_next = nlist[p + 1];
        if ((unsigned)e >= (unsigned)NE) continue;
        const bf16x8 f = *(const bf16x8*)(feats + (size_t)e * HID + lane * 8);
#pragma unroll
        for (int j = 0; j < 8; ++j) av[j] += bf2f((unsigned short)f[j]);
    }
    float4 o0 = make_float4(av[0], av[1], av[2], av[3]);
    float4 o1 = make_float4(av[4], av[5], av[6], av[7]);
    float* out = fsum + (size_t)w * HID + lane * 8;
    *reinterpret_cast<float4*>(out)     = o0;
    *reinterpret_cast<float4*>(out + 4) = o1;
}

// ---------------------------------------------------------------------------
extern "C" void kernel_launch(void* const* d_in, const int* in_sizes, int n_in,
                              void* d_out, int out_size, void* d_ws, size_t ws_size,
                              hipStream_t stream)
{
    const float* atom = (const float*)d_in[0];
    const float* edge = (const float*)d_in[1];
    const float* W_i  = (const float*)d_in[2];
    const float* Wq   = (const float*)d_in[3];
    const float* Wk   = (const float*)d_in[4];
    const float* Wv   = (const float*)d_in[5];
    const float* L1w  = (const float*)d_in[6];
    const float* L1b  = (const float*)d_in[7];
    const float* L2w  = (const float*)d_in[8];
    const float* L2b  = (const float*)d_in[9];
    const float* Wo   = (const float*)d_in[10];
    const float* bo   = (const float*)d_in[11];
    const int* src    = (const int*)d_in[12];
    const int* dst    = (const int*)d_in[13];
    const int* idx_kj = (const int*)d_in[14];
    const int* idx_ji = (const int*)d_in[15];

    const size_t RB = (size_t)NE * HID * 2;   // 102,400,000 B
    char* ws = (char*)d_ws;
    unsigned short* feats = (unsigned short*)(ws);
    unsigned short* qb    = (unsigned short*)(ws + RB);
    unsigned short* kb    = (unsigned short*)(ws + 2 * RB);
    unsigned short* vb    = (unsigned short*)d_out;     // NE*256 bf16 == d_out bytes
    unsigned short* vc    = feats;                      // v_clone overlays feats
    unsigned short* initA = qb;                         // NEP*192 bf16 = 76.8MB < RB
    unsigned short* h1    = kb;
    float*          fsum  = (float*)(ws + RB);          // NN*256 f32 == RB
    unsigned short* finalA = kb;                        // NNP*448 bf16 = 89.7MB < RB

    char* p = ws + 3 * RB;
    int* trip_off  = (int*)p; p += 800016;
    int* trip_cur  = (int*)p; p += 800016;
    int* trip_list = (int*)p; p += 2400000;
    int* trip_kj   = (int*)p; p += 2400000;
    int* node_off  = (int*)p; p += 400016;
    int* node_cur  = (int*)p; p += 400016;
    int* node_list = (int*)p; p += 800000;
    int* tmp_excl  = (int*)p; p += 800016;
    int* partials  = (int*)p; p += 1024;
    unsigned short* wiT = (unsigned short*)p; p += (size_t)256 * 192 * 2;
    unsigned short* wT0 = (unsigned short*)p; p += (size_t)10 * 65536 * 2;
    unsigned short* woT = (unsigned short*)p; p += (size_t)256 * 448 * 2;
    const size_t NEEDED = (size_t)(p - ws);
    if (ws_size < NEEDED) return;
    auto wT = [&](int i) { return wT0 + (size_t)i * 65536; };

    const int MT_E  = NEP / 128;                 // 1563 M-tiles (edge GEMMs)
    const int MT_E8 = ((MT_E + 7) / 8) * 8;      // 1568
    const int MT_N  = NNP / 128;                 // 782 (final GEMM)
    const int MT_N8 = ((MT_N + 7) / 8) * 8;      // 784

    // ---- weight convert/transpose/pad (bf16) ----
    wconv<<<192, 256, 0, stream>>>(W_i, wiT, 147, 192);
    wconv10<<<dim3(256, 10), 256, 0, stream>>>(Wq, Wk, Wv, L1w, L2w, wT0);
    wconv<<<448, 256, 0, stream>>>(Wo, woT, 389, 448);

    // ---- CSR build (triplets by idx_ji; edges by dst) ----
    hipMemsetAsync(trip_cur, 0, (size_t)NE * 4, stream);
    hipMemsetAsync(node_cur, 0, (size_t)NN * 4, stream);
    count_keys<<<(NT + 255) / 256, 256, 0, stream>>>(idx_ji, NT, NE, trip_cur);
    count_keys<<<(NE + 255) / 256, 256, 0, stream>>>(dst, NE, NN, node_cur);

    scan1<<<(NE + 1023) / 1024, 256, 0, stream>>>(trip_cur, NE, tmp_excl, partials);
    scan2<<<1, 256, 0, stream>>>(partials, (NE + 1023) / 1024);
    scan3<<<(NE + 255) / 256, 256, 0, stream>>>(tmp_excl, partials, trip_cur, NE, trip_off, trip_cur);
    fill_lists<<<(NT + 255) / 256, 256, 0, stream>>>(idx_ji, NT, NE, NT, trip_cur, trip_list);
    build_tripkj<<<(NT + 255) / 256, 256, 0, stream>>>(trip_list, idx_kj, trip_kj);

    scan1<<<(NN + 1023) / 1024, 256, 0, stream>>>(node_cur, NN, tmp_excl, partials);
    scan2<<<1, 256, 0, stream>>>(partials, (NN + 1023) / 1024);
    scan3<<<(NN + 255) / 256, 256, 0, stream>>>(tmp_excl, partials, node_cur, NN, node_off, node_cur);
    fill_lists<<<(NE + 255) / 256, 256, 0, stream>>>(dst, NE, NN, NE, node_cur, node_list);

    // ---- init: feats = relu(concat(atom[src], edge) @ W_i) ----
    {
        const long total = (long)NE * 192;
        build_initA<<<(int)((total + 255) / 256), 256, 0, stream>>>(atom, edge, src, initA);
    }
    gemm128<1, true><<<MT_E8 * 2, 256, 0, stream>>>(initA, wiT, nullptr, nullptr,
                                                    feats, MT_E, NE, 192);

    // ---- 2 attention layers ----
    for (int l = 0; l < 2; ++l) {
        const float* l1b = L1b + (size_t)l * 256;
        const float* l2b = L2b + (size_t)l * 256;

        gemm128_qkv<<<MT_E8 * 6, 256, 0, stream>>>(
            feats, wT(l * 5 + 0), wT(l * 5 + 1), wT(l * 5 + 2), qb, kb, vb, MT_E);

        gather_v<<<(NE * 32) / 256, 256, 0, stream>>>(qb, kb, vb, trip_off, trip_kj, vc);

        // h1 = relu(vc @ L1 + b1); feats = v + relu(h1 @ L2 + b2)
        gemm128<3, true><<<MT_E8 * 2, 256, 0, stream>>>(vc, wT(l * 5 + 3), l1b,
                                                        nullptr, h1, MT_E, NE, 256);
        gemm128<7, true><<<MT_E8 * 2, 256, 0, stream>>>(h1, wT(l * 5 + 4), l2b,
                                                        vb, feats, MT_E, NE, 256);
    }

    // ---- edge -> node gather, final projection ----
    gather_node<<<(NN * 32) / 256, 256, 0, stream>>>(feats, node_off, node_list, fsum);
    {
        const long total = (long)NNP * 448;
        build_finalA<<<(int)((total + 255) / 256), 256, 0, stream>>>(atom, fsum, finalA);
    }
    gemm128<3, false><<<MT_N8 * 2, 256, 0, stream>>>(finalA, woT, bo, nullptr,
                                                     d_out, MT_N, NN, 448);
}

// Round 13
// 1278.322 us; speedup vs baseline: 1.0410x; 1.0410x over previous
//
#include <hip/hip_runtime.h>
#include <stdint.h>

#define NN 100000
#define NNP 100096          // NN padded to multiple of 128
#define NE 200000
#define NEP 200064          // NE padded to multiple of 128
#define NT 600000
#define HID 256

typedef __attribute__((ext_vector_type(8))) short bf16x8;
typedef __attribute__((ext_vector_type(4))) float f32x4;

__device__ __forceinline__ float bf2f(unsigned short u) {
    union { unsigned int i; float f; } x; x.i = ((unsigned int)u) << 16; return x.f;
}
__device__ __forceinline__ unsigned short f2bf(float f) {
    union { float f; unsigned int i; } x; x.f = f;
    unsigned int r = (x.i + 0x7FFFu + ((x.i >> 16) & 1u)) >> 16;
    return (unsigned short)r;
}

// async global->LDS, 16B per lane; LDS dest = wave-uniform base + lane*16
__device__ __forceinline__ void gload16(const void* g, void* l) {
    __builtin_amdgcn_global_load_lds(
        (const __attribute__((address_space(1))) void*)g,
        (__attribute__((address_space(3))) void*)l, 16, 0, 0);
}

// ---------------------------------------------------------------------------
// m97-style GEMM core (round-11 proven form): 4 waves (2x2), wave tile 64x64,
// BK=64, 32 KB LDS, 2-barrier loop, gload_lds staging, rule-21 swizzle pair.
// ROUND-12 LESSON: C^T operand-swap epilogue regressed (-7%) — keep direct.
// REGISTER BUDGET [rounds 8/10]: pool = 512 wave-regs/SIMD, unified VGPR+AGPR.
// Needs 64 acc + ~60 VGPR = 124; bounds(256,4) caps 128: OK. (256,5)=102 and
// (512,6)=85 both spilled acc to scratch (WRITE_SIZE x1.8-5.7, MfmaUtil /2).
// ---------------------------------------------------------------------------
template<int FLAGS, bool CBF>
__device__ __forceinline__
void gemm128_core(const unsigned short* __restrict__ A,
                  const unsigned short* __restrict__ BT,
                  const float* __restrict__ bias,
                  const unsigned short* __restrict__ res,
                  void* __restrict__ Cv, int row0, int col0,
                  int Mreal, int Kpad,
                  unsigned short* Asb, unsigned short* Bsb)
{
    const int t    = threadIdx.x;
    const int lane = t & 63;
    const int wv   = t >> 6;          // 0..3
    const int wr   = wv >> 1;         // wave row half
    const int wc   = wv & 1;          // wave col half
    const int l15  = lane & 15;
    const int lk   = lane >> 4;
    const int sub  = lane >> 3;       // staging sub-row 0..7
    const int schk = lane & 7;        // staging 16B chunk 0..7

    f32x4 acc[4][4];
#pragma unroll
    for (int i = 0; i < 4; ++i)
#pragma unroll
        for (int j = 0; j < 4; ++j) acc[i][j] = (f32x4){0.f, 0.f, 0.f, 0.f};

    const int nt = Kpad >> 6;
    for (int kt = 0; kt < nt; ++kt) {
        const int k0 = kt << 6;
        // stage A tile 128x64 (16 segs of 8 rows; wave wv does segs wv*4+j)
#pragma unroll
        for (int j = 0; j < 4; ++j) {
            const int ii = wv * 4 + j;
            const int r  = ii * 8 + sub;
            const int cg = schk ^ (r & 7);
            gload16(A + (size_t)(row0 + r) * Kpad + k0 + cg * 8, Asb + ii * 512);
        }
        // stage B tile 128x64 (B rows = output cols col0..col0+127)
#pragma unroll
        for (int j = 0; j < 4; ++j) {
            const int ii = wv * 4 + j;
            const int r  = ii * 8 + sub;
            const int cg = schk ^ (r & 7);
            gload16(BT + (size_t)(col0 + r) * Kpad + k0 + cg * 8, Bsb + ii * 512);
        }
        __syncthreads();     // compiler drains vmcnt before s_barrier
#pragma unroll
        for (int ks = 0; ks < 2; ++ks) {
            bf16x8 af[4], bfg[4];
#pragma unroll
            for (int mi = 0; mi < 4; ++mi) {
                const int r = wr * 64 + mi * 16 + l15;
                const int c = ks * 4 + lk;
                af[mi] = *(const bf16x8*)((const char*)Asb
                          + r * 128 + ((c ^ (r & 7)) << 4));
            }
#pragma unroll
            for (int ni = 0; ni < 4; ++ni) {
                const int r = wc * 64 + ni * 16 + l15;
                const int c = ks * 4 + lk;
                bfg[ni] = *(const bf16x8*)((const char*)Bsb
                           + r * 128 + ((c ^ (r & 7)) << 4));
            }
#pragma unroll
            for (int mi = 0; mi < 4; ++mi)
#pragma unroll
                for (int ni = 0; ni < 4; ++ni)
                    acc[mi][ni] = __builtin_amdgcn_mfma_f32_16x16x32_bf16(
                        af[mi], bfg[ni], acc[mi][ni], 0, 0, 0);
        }
        __syncthreads();     // reads done before next stage overwrites
    }

    // epilogue: D col=l&15, row=(l>>4)*4+reg  [m89-verified]
#pragma unroll
    for (int mi = 0; mi < 4; ++mi) {
#pragma unroll
        for (int r = 0; r < 4; ++r) {
            const int row = row0 + wr * 64 + mi * 16 + lk * 4 + r;
            if (row >= Mreal) continue;
#pragma unroll
            for (int ni = 0; ni < 4; ++ni) {
                const int col = col0 + wc * 64 + ni * 16 + l15;
                float o = acc[mi][ni][r];
                if (FLAGS & 2) o += bias[col];
                if (FLAGS & 1) o = fmaxf(o, 0.f);
                if (FLAGS & 4) o += bf2f(res[(size_t)row * HID + col]);
                if (CBF) ((unsigned short*)Cv)[(size_t)row * HID + col] = f2bf(o);
                else     ((float*)Cv)[(size_t)row * HID + col] = o;
            }
        }
    }
}

// XCD-aware swizzle [T1]: x = xcd + 8*(member + MEMBERS*local_group).
template<int FLAGS, bool CBF>
__global__ __launch_bounds__(256, 4)
void gemm128(const unsigned short* __restrict__ A,
             const unsigned short* __restrict__ BT,
             const float* __restrict__ bias,
             const unsigned short* __restrict__ res,
             void* __restrict__ Cv, int Mtiles, int Mreal, int Kpad)
{
    __shared__ alignas(16) unsigned short Asb[128 * 64];
    __shared__ alignas(16) unsigned short Bsb[128 * 64];
    const int x   = blockIdx.x;
    const int xcd = x & 7;
    const int ii  = x >> 3;
    const int g   = (ii >> 1) * 8 + xcd;     // tile-group = M tile
    const int ch  = ii & 1;
    if (g >= Mtiles) return;
    gemm128_core<FLAGS, CBF>(A, BT, bias, res, Cv, g * 128, ch * 128,
                             Mreal, Kpad, Asb, Bsb);
}

// qkv: grid.x = Mtiles8 * 6; 6 members (3 proj x 2 halves) share one A tile
__global__ __launch_bounds__(256, 4)
void gemm128_qkv(const unsigned short* __restrict__ A,
                 const unsigned short* __restrict__ BTq,
                 const unsigned short* __restrict__ BTk,
                 const unsigned short* __restrict__ BTv,
                 unsigned short* __restrict__ Cq,
                 unsigned short* __restrict__ Ck,
                 unsigned short* __restrict__ Cvp, int Mtiles)
{
    __shared__ alignas(16) unsigned short Asb[128 * 64];
    __shared__ alignas(16) unsigned short Bsb[128 * 64];
    const int x   = blockIdx.x;
    const int xcd = x & 7;
    const int ii  = x >> 3;
    const int g   = (ii / 6) * 8 + xcd;
    const int j   = ii % 6;
    if (g >= Mtiles) return;
    const int proj = j >> 1;
    const int ch   = j & 1;
    const unsigned short* BT = (proj == 0) ? BTq : (proj == 1) ? BTk : BTv;
    unsigned short*       C  = (proj == 0) ? Cq  : (proj == 1) ? Ck  : Cvp;
    gemm128_core<0, true>(A, BT, nullptr, nullptr, C, g * 128, ch * 128,
                          NE, 256, Asb, Bsb);
}

// ---------------------------------------------------------------------------
__global__ __launch_bounds__(256)
void wconv(const float* __restrict__ W, unsigned short* __restrict__ BT,
           int Kreal, int Kpad)
{
    const int idx = blockIdx.x * 256 + threadIdx.x;
    const int n = idx / Kpad, kp = idx - n * Kpad;
    float v = (kp < Kreal) ? W[(size_t)kp * HID + n] : 0.f;
    BT[idx] = f2bf(v);
}

__global__ __launch_bounds__(256)
void wconv10(const float* __restrict__ Wq, const float* __restrict__ Wk,
             const float* __restrict__ Wv, const float* __restrict__ L1w,
             const float* __restrict__ L2w, unsigned short* __restrict__ outbase)
{
    const int y = blockIdx.y;
    const int l = y / 5, which = y - l * 5;
    const float* src;
    switch (which) {
        case 0: src = Wq;  break;
        case 1: src = Wk;  break;
        case 2: src = Wv;  break;
        case 3: src = L1w; break;
        default: src = L2w; break;
    }
    src += (size_t)l * 65536;
    const int idx = blockIdx.x * 256 + threadIdx.x;
    const int n = idx >> 8, kp = idx & 255;
    outbase[(size_t)y * 65536 + idx] = f2bf(src[(size_t)kp * HID + n]);
}

// ---------------------------------------------------------------------------
__global__ __launch_bounds__(256)
void build_initA(const float* __restrict__ atom, const float* __restrict__ edge,
                 const int* __restrict__ src, unsigned short* __restrict__ out)
{
    const long total = (long)NE * 192;
    long idx = (long)blockIdx.x * blockDim.x + threadIdx.x;
    if (idx >= total) return;
    const int e = (int)(idx / 192);
    const int c = (int)(idx - (long)e * 192);
    float v = 0.f;
    if (c < 133)      v = atom[(size_t)src[e] * 133 + c];
    else if (c < 147) v = edge[(size_t)e * 14 + (c - 133)];
    out[idx] = f2bf(v);
}

__global__ __launch_bounds__(256)
void build_finalA(const float* __restrict__ atom, const float* __restrict__ fsum,
                  unsigned short* __restrict__ out)
{
    const long total = (long)NNP * 448;
    long idx = (long)blockIdx.x * blockDim.x + threadIdx.x;
    if (idx >= total) return;
    const int n = (int)(idx / 448);
    const int c = (int)(idx - (long)n * 448);
    float v = 0.f;
    if (n < NN) {
        if (c < 133)      v = atom[(size_t)n * 133 + c];
        else if (c < 389) v = fsum[(size_t)n * 256 + (c - 133)];
    }
    out[idx] = f2bf(v);
}

// ---------------------------------------------------------------------------
// Combined CSR build: one counts/offsets array covering triplet keys [0,NE)
// and node keys [NE, NE+NN). One scan chain. plist is the combined payload:
//   [0, NT)       : kj value per triplet slot (tkj folded into fill)
//   [NT, NT+NE)   : edge id per node slot
// ---------------------------------------------------------------------------
__global__ __launch_bounds__(256)
void count_keys(const int* __restrict__ key, int n, int nkeys, int* __restrict__ cnt)
{
    const int i = blockIdx.x * 256 + threadIdx.x;
    if (i < n) {
        const int kk = key[i];
        if ((unsigned)kk < (unsigned)nkeys) atomicAdd(&cnt[kk], 1);
    }
}

// fill triplet slots with resolved kj values
__global__ __launch_bounds__(256)
void fill_trip(const int* __restrict__ idx_ji, const int* __restrict__ idx_kj,
               int* __restrict__ cur, int* __restrict__ plist)
{
    const int i = blockIdx.x * 256 + threadIdx.x;
    if (i >= NT) return;
    const int kk = idx_ji[i];
    if ((unsigned)kk >= (unsigned)NE) return;
    const int pos = atomicAdd(&cur[kk], 1);
    if ((unsigned)pos < (unsigned)NT) plist[pos] = idx_kj[i];
}

// fill node slots with edge ids (absolute positions in [NT, NT+NE))
__global__ __launch_bounds__(256)
void fill_node(const int* __restrict__ dst, int* __restrict__ cur,
               int* __restrict__ plist)
{
    const int i = blockIdx.x * 256 + threadIdx.x;
    if (i >= NE) return;
    const int kk = dst[i];
    if ((unsigned)kk >= (unsigned)NN) return;
    const int pos = atomicAdd(&cur[NE + kk], 1);
    if ((unsigned)pos < (unsigned)(NT + NE)) plist[pos] = i;
}

// per-block (2048 elems, 8/thread) exclusive scan; partials out (<=256 blocks)
__global__ __launch_bounds__(256)
void scan1(const int* __restrict__ in, int n, int* __restrict__ excl,
           int* __restrict__ part)
{
    __shared__ int sh[256];
    const int t = threadIdx.x;
    const int base = blockIdx.x * 2048 + t * 8;
    int v[8]; int s = 0;
#pragma unroll
    for (int j = 0; j < 8; ++j) { v[j] = (base + j < n) ? in[base + j] : 0; s += v[j]; }
    sh[t] = s; __syncthreads();
    for (int off = 1; off < 256; off <<= 1) {
        int x = (t >= off) ? sh[t - off] : 0;
        __syncthreads();
        sh[t] += x;
        __syncthreads();
    }
    int ex = sh[t] - s;
#pragma unroll
    for (int j = 0; j < 8; ++j) { if (base + j < n) excl[base + j] = ex; ex += v[j]; }
    if (t == 255) part[blockIdx.x] = sh[255];
}

__global__ __launch_bounds__(256)
void scan2(int* __restrict__ part, int nparts)
{
    __shared__ int sh[256];
    const int t = threadIdx.x;
    const int v = (t < nparts) ? part[t] : 0;
    sh[t] = v; __syncthreads();
    for (int off = 1; off < 256; off <<= 1) {
        int x = (t >= off) ? sh[t - off] : 0;
        __syncthreads();
        sh[t] += x;
        __syncthreads();
    }
    if (t < nparts) part[t] = sh[t] - v;
}

// offs[i] = cur[i] = excl[i] + part[i/2048]; offs[n] = total.
// counts/cur alias intentionally (non-restrict); read c before write.
__global__ __launch_bounds__(256)
void scan3(const int* __restrict__ excl, const int* __restrict__ part,
           const int* counts, int n, int* __restrict__ offs, int* cur)
{
    const int i = blockIdx.x * 256 + threadIdx.x;
    if (i >= n) return;
    const int v = excl[i] + part[i >> 11];
    const int c = counts[i];
    offs[i] = v;
    cur[i] = v;
    if (i == n - 1) offs[n] = v + c;
}

// ---------------------------------------------------------------------------
// Fused attention gather: 32 lanes per edge (2 edges/wave), bf16x8 loads,
// pre-resolved kj list (plist triplet region) with one-deep prefetch.
// ---------------------------------------------------------------------------
__global__ __launch_bounds__(256)
void gather_v(const unsigned short* __restrict__ q, const unsigned short* __restrict__ k,
              const unsigned short* __restrict__ v,
              const int* __restrict__ toff, const int* __restrict__ tkj,
              unsigned short* __restrict__ vc)
{
    const long gtid = (long)blockIdx.x * blockDim.x + threadIdx.x;
    const int w    = (int)(gtid >> 5);
    const int lane = threadIdx.x & 31;
    if (w >= NE) return;
    int beg = toff[w], end = toff[w + 1];
    if (beg < 0) beg = 0;
    if (end > NT) end = NT;

    const bf16x8 kv = *(const bf16x8*)(k + (size_t)w * HID + lane * 8);
    float kf[8];
#pragma unroll
    for (int j = 0; j < 8; ++j) kf[j] = bf2f((unsigned short)kv[j]);

    float av[8];
#pragma unroll
    for (int j = 0; j < 8; ++j) av[j] = 0.f;
    float den = 0.f;

    int kj_next = (beg < end) ? tkj[beg] : -1;
    for (int p = beg; p < end; ++p) {
        const int kj = kj_next;
        if (p + 1 < end) kj_next = tkj[p + 1];
        if ((unsigned)kj >= (unsigned)NE) continue;
        const bf16x8 qv = *(const bf16x8*)(q + (size_t)kj * HID + lane * 8);
        float s = 0.f;
#pragma unroll
        for (int j = 0; j < 8; ++j) s += bf2f((unsigned short)qv[j]) * kf[j];
        s += __shfl_xor(s, 1);
        s += __shfl_xor(s, 2);
        const float lr = (s > 0.f) ? s : 0.2f * s;
        const float a  = __expf(lr);
        den += a;
        const bf16x8 vv = *(const bf16x8*)(v + (size_t)kj * HID + lane * 8);
#pragma unroll
        for (int j = 0; j < 8; ++j) av[j] += a * bf2f((unsigned short)vv[j]);
    }
    const float inv = (den != 0.f) ? 1.f / den : 0.f;
    bf16x8 o;
#pragma unroll
    for (int j = 0; j < 8; ++j) o[j] = (short)f2bf(av[j] * inv);
    *(bf16x8*)(vc + (size_t)w * HID + lane * 8) = o;
}

// ---------------------------------------------------------------------------
// edge->node gather: 32 lanes per node, bf16x8 loads, f32 out.
// noff points at the node region (offs+NE); positions are absolute in plist.
// ---------------------------------------------------------------------------
__global__ __launch_bounds__(256)
void gather_node(const unsigned short* __restrict__ feats,
                 const int* __restrict__ noff, const int* __restrict__ nlist,
                 float* __restrict__ fsum)
{
    const long gtid = (long)blockIdx.x * blockDim.x + threadIdx.x;
    const int w    = (int)(gtid >> 5);
    const int lane = threadIdx.x & 31;
    if (w >= NN) return;
    int beg = noff[w], end = noff[w + 1];
    if (beg < 0) beg = 0;
    if (end > NT + NE) end = NT + NE;
    float av[8];
#pragma unroll
    for (int j = 0; j < 8; ++j) av[j] = 0.f;
    int e_next = (beg < end) ? nlist[beg] : -1;
    for (int p = beg; p < end; ++p) {
        const int e = e_next;
        if (p + 1 < end) e_next = nlist[p + 1];
        if ((unsigned)e >= (unsigned)NE) continue;
        const bf16x8 f = *(const bf16x8*)(feats + (size_t)e * HID + lane * 8);
#pragma unroll
        for (int j = 0; j < 8; ++j) av[j] += bf2f((unsigned short)f[j]);
    }
    float4 o0 = make_float4(av[0], av[1], av[2], av[3]);
    float4 o1 = make_float4(av[4], av[5], av[6], av[7]);
    float* out = fsum + (size_t)w * HID + lane * 8;
    *reinterpret_cast<float4*>(out)     = o0;
    *reinterpret_cast<float4*>(out + 4) = o1;
}

// ---------------------------------------------------------------------------
extern "C" void kernel_launch(void* const* d_in, const int* in_sizes, int n_in,
                              void* d_out, int out_size, void* d_ws, size_t ws_size,
                              hipStream_t stream)
{
    const float* atom = (const float*)d_in[0];
    const float* edge = (const float*)d_in[1];
    const float* W_i  = (const float*)d_in[2];
    const float* Wq   = (const float*)d_in[3];
    const float* Wk   = (const float*)d_in[4];
    const float* Wv   = (const float*)d_in[5];
    const float* L1w  = (const float*)d_in[6];
    const float* L1b  = (const float*)d_in[7];
    const float* L2w  = (const float*)d_in[8];
    const float* L2b  = (const float*)d_in[9];
    const float* Wo   = (const float*)d_in[10];
    const float* bo   = (const float*)d_in[11];
    const int* src    = (const int*)d_in[12];
    const int* dst    = (const int*)d_in[13];
    const int* idx_kj = (const int*)d_in[14];
    const int* idx_ji = (const int*)d_in[15];

    const size_t RB = (size_t)NE * HID * 2;   // 102,400,000 B
    char* ws = (char*)d_ws;
    unsigned short* feats = (unsigned short*)(ws);
    unsigned short* qb    = (unsigned short*)(ws + RB);
    unsigned short* kb    = (unsigned short*)(ws + 2 * RB);
    unsigned short* vb    = (unsigned short*)d_out;     // NE*256 bf16 == d_out bytes
    unsigned short* vc    = feats;                      // v_clone overlays feats
    unsigned short* initA = qb;                         // NEP*192 bf16 = 76.8MB < RB
    unsigned short* h1    = kb;
    float*          fsum  = (float*)(ws + RB);          // NN*256 f32 == RB
    unsigned short* finalA = kb;                        // NNP*448 bf16 = 89.7MB < RB

    const int NK = NE + NN;                 // combined key count
    char* p = ws + 3 * RB;
    int* offs     = (int*)p; p += ((size_t)NK + 16) * 4;
    int* cur      = (int*)p; p += ((size_t)NK + 16) * 4;
    int* plist    = (int*)p; p += (size_t)(NT + NE) * 4;
    int* tmp_excl = (int*)p; p += ((size_t)NK + 16) * 4;
    int* partials = (int*)p; p += 1024;
    unsigned short* wiT = (unsigned short*)p; p += (size_t)256 * 192 * 2;
    unsigned short* wT0 = (unsigned short*)p; p += (size_t)10 * 65536 * 2;
    unsigned short* woT = (unsigned short*)p; p += (size_t)256 * 448 * 2;
    const size_t NEEDED = (size_t)(p - ws);
    if (ws_size < NEEDED) return;
    auto wT = [&](int i) { return wT0 + (size_t)i * 65536; };

    const int MT_E  = NEP / 128;                 // 1563 M-tiles (edge GEMMs)
    const int MT_E8 = ((MT_E + 7) / 8) * 8;      // 1568
    const int MT_N  = NNP / 128;                 // 782 (final GEMM)
    const int MT_N8 = ((MT_N + 7) / 8) * 8;      // 784
    const int NPARTS = (NK + 2047) / 2048;       // 147 <= 256

    // ---- weight convert/transpose/pad (bf16) ----
    wconv<<<192, 256, 0, stream>>>(W_i, wiT, 147, 192);
    wconv10<<<dim3(256, 10), 256, 0, stream>>>(Wq, Wk, Wv, L1w, L2w, wT0);
    wconv<<<448, 256, 0, stream>>>(Wo, woT, 389, 448);

    // ---- combined CSR build ----
    hipMemsetAsync(cur, 0, (size_t)NK * 4, stream);
    count_keys<<<(NT + 255) / 256, 256, 0, stream>>>(idx_ji, NT, NE, cur);
    count_keys<<<(NE + 255) / 256, 256, 0, stream>>>(dst, NE, NN, cur + NE);
    scan1<<<NPARTS, 256, 0, stream>>>(cur, NK, tmp_excl, partials);
    scan2<<<1, 256, 0, stream>>>(partials, NPARTS);
    scan3<<<(NK + 255) / 256, 256, 0, stream>>>(tmp_excl, partials, cur, NK, offs, cur);
    fill_trip<<<(NT + 255) / 256, 256, 0, stream>>>(idx_ji, idx_kj, cur, plist);
    fill_node<<<(NE + 255) / 256, 256, 0, stream>>>(dst, cur, plist);

    // ---- init: feats = relu(concat(atom[src], edge) @ W_i) ----
    {
        const long total = (long)NE * 192;
        build_initA<<<(int)((total + 255) / 256), 256, 0, stream>>>(atom, edge, src, initA);
    }
    gemm128<1, true><<<MT_E8 * 2, 256, 0, stream>>>(initA, wiT, nullptr, nullptr,
                                                    feats, MT_E, NE, 192);

    // ---- 2 attention layers ----
    for (int l = 0; l < 2; ++l) {
        const float* l1b = L1b + (size_t)l * 256;
        const float* l2b = L2b + (size_t)l * 256;

        gemm128_qkv<<<MT_E8 * 6, 256, 0, stream>>>(
            feats, wT(l * 5 + 0), wT(l * 5 + 1), wT(l * 5 + 2), qb, kb, vb, MT_E);

        gather_v<<<(NE * 32) / 256, 256, 0, stream>>>(qb, kb, vb, offs, plist, vc);

        // h1 = relu(vc @ L1 + b1); feats = v + relu(h1 @ L2 + b2)
        gemm128<3, true><<<MT_E8 * 2, 256, 0, stream>>>(vc, wT(l * 5 + 3), l1b,
                                                        nullptr, h1, MT_E, NE, 256);
        gemm128<7, true><<<MT_E8 * 2, 256, 0, stream>>>(h1, wT(l * 5 + 4), l2b,
                                                        vb, feats, MT_E, NE, 256);
    }

    // ---- edge -> node gather, final projection ----
    gather_node<<<(NN * 32) / 256, 256, 0, stream>>>(feats, offs + NE, plist, fsum);
    {
        const long total = (long)NNP * 448;
        build_finalA<<<(int)((total + 255) / 256), 256, 0, stream>>>(atom, fsum, finalA);
    }
    gemm128<3, false><<<MT_N8 * 2, 256, 0, stream>>>(finalA, woT, bo, nullptr,
                                                     d_out, MT_N, NN, 448);
}